// Round 1
// baseline (124576.929 us; speedup 1.0000x reference)
//
#include <hip/hip_runtime.h>
#include <stdint.h>

#define LL 4
#define BATCH 128
#define TSEQ 1024
#define HID 512
#define G4 2048
#define BGR 8     // batch groups (16 batches each)
#define BB 16     // batches per group
#define KSL 32    // hidden-slice WGs per group (16 cols each)

typedef __attribute__((ext_vector_type(8))) short s8v;   // 8 x bf16 fragment
typedef __attribute__((ext_vector_type(4))) float f4v;   // MFMA accumulator

__device__ __forceinline__ unsigned short f2bf(float f) {
  union { float f; unsigned u; } v; v.f = f;
  return (unsigned short)((v.u + 0x7fffu + ((v.u >> 16) & 1u)) >> 16);  // RNE
}

__device__ __forceinline__ float fsig(float x) { return 1.f / (1.f + __expf(-x)); }

__device__ __forceinline__ float ftanh(float x) {
  float a = __builtin_fabsf(x);
  float e = __expf(-2.f * a);
  float t = (1.f - e) / (1.f + e);
  return x < 0.f ? -t : t;
}

__global__ void cvt_f32_bf16(const float* __restrict__ in, unsigned short* __restrict__ out, int n4) {
  int stride = gridDim.x * blockDim.x;
  for (int i = blockIdx.x * blockDim.x + threadIdx.x; i < n4; i += stride) {
    f4v v = ((const f4v*)in)[i];
    union { unsigned short u[4]; unsigned long long d; } o;
    o.u[0] = f2bf(v.x); o.u[1] = f2bf(v.y); o.u[2] = f2bf(v.z); o.u[3] = f2bf(v.w);
    ((unsigned long long*)out)[i] = o.d;
  }
}

// Persistent per-layer LSTM kernel.
// Grid: 256 WGs = 8 batch-groups x 32 hidden-slices. blockIdx & 7 = batch group
// (XCD round-robin keeps a group's 32 WGs on one XCD for h-exchange locality).
// Each WG: 16 batches x 16 hidden cols. K=1024 fused contraction (512 x-part +
// 512 h-part) split across the 4 waves; weight fragments held in VGPRs.
__global__ void __launch_bounds__(256, 1) lstm_layer(
    const unsigned short* __restrict__ xin,   // (B,T,512) bf16 layer input
    unsigned short* __restrict__ seqout,      // (B,T,512) bf16 layer output
    const unsigned short* __restrict__ wih,   // (2048,512) bf16
    const unsigned short* __restrict__ whh,   // (2048,512) bf16
    const float* __restrict__ bih,
    const float* __restrict__ bhh,
    const float* __restrict__ h0,             // (B,512) fp32
    const float* __restrict__ c0,             // (B,512) fp32
    unsigned short* __restrict__ hbuf,        // 2 * B*512 bf16 ping-pong
    unsigned int* __restrict__ bars,          // BGR counters, 128B apart (zeroed)
    float* __restrict__ cout,                 // (B,512) fp32 final c
    int write_seq)
{
  const int tid  = threadIdx.x;
  const int wave = tid >> 6;
  const int lane = tid & 63;
  const int lm   = lane & 15;   // A-frag row (batch) / B-frag row (gate col)
  const int quad = lane >> 4;

  const int bid = blockIdx.x;
  const int grp = bid & 7;      // batch group
  const int kap = bid >> 3;     // hidden slice 0..31
  const int bg0 = grp * BB;

  __shared__ float gates[4][16][68];  // [wave partial][batch][4*16 gate cols + pad]

  // ---- load this WG's weight fragments into registers (held all 1024 steps) ----
  // wave w covers k in [256w, 256w+256): waves 0,1 -> w_ih, waves 2,3 -> w_hh
  const unsigned short* wsel = (wave < 2) ? wih : whh;
  const int kbase = (wave & 1) * 256;
  s8v breg[4][8];
#pragma unroll
  for (int g = 0; g < 4; ++g) {
    const size_t row = (size_t)(g * 512 + kap * 16 + lm);  // gate-major weight row
#pragma unroll
    for (int s = 0; s < 8; ++s)
      breg[g][s] = *(const s8v*)(wsel + row * HID + kbase + s * 32 + quad * 8);
  }

  // ---- per-thread (batch, hidden col) ownership for the elementwise part ----
  const int b_i  = tid >> 4;
  const int kk   = tid & 15;
  const int kcol = kap * 16 + kk;
  const int brow = bg0 + b_i;

  float bias[4];
#pragma unroll
  for (int g = 0; g < 4; ++g) bias[g] = bih[g * 512 + kcol] + bhh[g * 512 + kcol];

  float c = c0[(size_t)brow * HID + kcol];
  hbuf[(size_t)brow * HID + kcol] = f2bf(h0[(size_t)brow * HID + kcol]);

  unsigned int* bar = bars + grp * 32;
  unsigned bcount = 0;

  const int arow = bg0 + lm;                       // batch row for A fragments
  const size_t xrow = (size_t)arow * TSEQ * HID;
  const int koffA = kbase + quad * 8;

  // Group barrier: monotonic counter, agent-scope release/acquire. Bounded spin
  // so a sync failure produces a wrong answer instead of a hang.
#define GROUP_BARRIER()                                                          \
  do {                                                                           \
    __threadfence();                                                             \
    __syncthreads();                                                             \
    if (tid == 0) {                                                              \
      ++bcount;                                                                  \
      __hip_atomic_fetch_add(bar, 1u, __ATOMIC_RELEASE, __HIP_MEMORY_SCOPE_AGENT); \
      unsigned tgt = bcount * KSL;                                               \
      int guard = 0;                                                             \
      while (__hip_atomic_load(bar, __ATOMIC_ACQUIRE, __HIP_MEMORY_SCOPE_AGENT) < tgt \
             && ++guard < (1 << 18)) { }                                         \
    }                                                                            \
    __syncthreads();                                                             \
  } while (0)

  GROUP_BARRIER();  // h0 visible group-wide

  for (int t = 0; t < TSEQ; ++t) {
    const unsigned short* hprev = hbuf + (size_t)(t & 1) * BATCH * HID;
    unsigned short* hnext = hbuf + (size_t)((t & 1) ^ 1) * BATCH * HID;

    const unsigned short* abase =
        (wave < 2) ? (xin + xrow + (size_t)t * HID + koffA)
                   : (hprev + (size_t)arow * HID + koffA);

    f4v acc[4];
#pragma unroll
    for (int g = 0; g < 4; ++g) { f4v z = {0.f, 0.f, 0.f, 0.f}; acc[g] = z; }

#pragma unroll
    for (int s = 0; s < 8; ++s) {
      s8v a = *(const s8v*)(abase + s * 32);
#pragma unroll
      for (int g = 0; g < 4; ++g)
        acc[g] = __builtin_amdgcn_mfma_f32_16x16x32_bf16(a, breg[g][s], acc[g], 0, 0, 0);
    }

    // D layout (m89-verified): col = lane&15, row = quad*4 + reg
#pragma unroll
    for (int g = 0; g < 4; ++g)
#pragma unroll
      for (int r = 0; r < 4; ++r)
        gates[wave][quad * 4 + r][g * 16 + lm] = acc[g][r];

    __syncthreads();

    float gs[4];
#pragma unroll
    for (int g = 0; g < 4; ++g)
      gs[g] = bias[g] + gates[0][b_i][g * 16 + kk] + gates[1][b_i][g * 16 + kk]
                      + gates[2][b_i][g * 16 + kk] + gates[3][b_i][g * 16 + kk];

    float ig = fsig(gs[0]);
    float fg = fsig(gs[1]);
    float gg = ftanh(gs[2]);
    float og = fsig(gs[3]);
    c = fg * c + ig * gg;
    float h = og * ftanh(c);
    unsigned short hb = f2bf(h);

    hnext[(size_t)brow * HID + kcol] = hb;
    if (write_seq) seqout[(size_t)brow * TSEQ * HID + (size_t)t * HID + kcol] = hb;

    GROUP_BARRIER();
  }

  cout[(size_t)brow * HID + kcol] = c;
#undef GROUP_BARRIER
}

extern "C" void kernel_launch(void* const* d_in, const int* in_sizes, int n_in,
                              void* d_out, int out_size, void* d_ws, size_t ws_size,
                              hipStream_t stream)
{
  (void)in_sizes; (void)n_in; (void)out_size;
  const float* x   = (const float*)d_in[0];
  const float* h0  = (const float*)d_in[1];
  const float* c0  = (const float*)d_in[2];
  const float* wih = (const float*)d_in[3];
  const float* whh = (const float*)d_in[4];
  const float* bih = (const float*)d_in[5];
  const float* bhh = (const float*)d_in[6];
  float* out = (float*)d_out;

  const size_t seq_elems = (size_t)BATCH * TSEQ * HID;  // 67,108,864
  const size_t w_elems   = (size_t)LL * G4 * HID;       // 4,194,304

  unsigned short* seqA = (unsigned short*)d_ws;          // layer ping buffer (holds bf16 x first)
  unsigned short* seqB = seqA + seq_elems;               // layer pong buffer
  unsigned short* wihb = seqB + seq_elems;
  unsigned short* whhb = wihb + w_elems;
  unsigned short* hbuf = whhb + w_elems;                 // 2 * B*H
  unsigned int*   bars = (unsigned int*)(hbuf + 2 * (size_t)BATCH * HID);

  size_t need = (2 * seq_elems + 2 * w_elems + 2 * (size_t)BATCH * HID) * 2
              + (size_t)BGR * 32 * 4;
  if (ws_size < need) return;  // fail visibly rather than corrupt memory

  cvt_f32_bf16<<<4096, 256, 0, stream>>>(x,   seqA, (int)(seq_elems / 4));
  cvt_f32_bf16<<<2048, 256, 0, stream>>>(wih, wihb, (int)(w_elems / 4));
  cvt_f32_bf16<<<2048, 256, 0, stream>>>(whh, whhb, (int)(w_elems / 4));

  for (int l = 0; l < LL; ++l) {
    hipMemsetAsync(bars, 0, BGR * 32 * sizeof(unsigned), stream);
    const unsigned short* in_p  = (l & 1) ? seqB : seqA;
    unsigned short*       out_p = (l & 1) ? seqA : seqB;
    const unsigned short* wih_p = wihb + (size_t)l * G4 * HID;
    const unsigned short* whh_p = whhb + (size_t)l * G4 * HID;
    const float* bih_p = bih + l * G4;
    const float* bhh_p = bhh + l * G4;
    const float* h0_p  = h0 + (size_t)l * BATCH * HID;
    const float* c0_p  = c0 + (size_t)l * BATCH * HID;
    float* cout_p = out + (size_t)l * BATCH * HID;
    int wsflag = (l < LL - 1) ? 1 : 0;
    unsigned short* hbuf_p = hbuf;
    unsigned int* bars_p = bars;
    void* args[] = { &in_p, &out_p, &wih_p, &whh_p, &bih_p, &bhh_p,
                     &h0_p, &c0_p, &hbuf_p, &bars_p, &cout_p, &wsflag };
    hipLaunchCooperativeKernel(lstm_layer, dim3(256), dim3(256), args, 0, stream);
  }
}

// Round 2
// 16596.391 us; speedup vs baseline: 7.5063x; 7.5063x over previous
//
#include <hip/hip_runtime.h>
#include <stdint.h>

#define LL 4
#define BATCH 128
#define TSEQ 1024
#define HID 512
#define G4 2048
#define BGR 8     // batch groups (16 batches each)
#define BB 16     // batches per group
#define KSL 32    // hidden-slice WGs per group (16 cols each)

typedef __attribute__((ext_vector_type(8))) short s8v;   // 8 x bf16 fragment
typedef __attribute__((ext_vector_type(4))) float f4v;   // MFMA accumulator

__device__ __forceinline__ unsigned short f2bf(float f) {
  union { float f; unsigned u; } v; v.f = f;
  return (unsigned short)((v.u + 0x7fffu + ((v.u >> 16) & 1u)) >> 16);  // RNE
}

__device__ __forceinline__ float fsig(float x) { return 1.f / (1.f + __expf(-x)); }

__device__ __forceinline__ float ftanh(float x) {
  float a = __builtin_fabsf(x);
  float e = __expf(-2.f * a);
  float t = (1.f - e) / (1.f + e);
  return x < 0.f ? -t : t;
}

__global__ void cvt_f32_bf16(const float* __restrict__ in, unsigned short* __restrict__ out, int n4) {
  int stride = gridDim.x * blockDim.x;
  for (int i = blockIdx.x * blockDim.x + threadIdx.x; i < n4; i += stride) {
    f4v v = ((const f4v*)in)[i];
    union { unsigned short u[4]; unsigned long long d; } o;
    o.u[0] = f2bf(v.x); o.u[1] = f2bf(v.y); o.u[2] = f2bf(v.z); o.u[3] = f2bf(v.w);
    ((unsigned long long*)out)[i] = o.d;
  }
}

// Persistent per-layer LSTM kernel.
// Grid: 256 WGs = 8 batch-groups x 32 hidden-slices; blockIdx&7 = group so the
// usual bid%8->XCD round-robin keeps a group on one XCD (perf heuristic only).
// CORRECTNESS does not depend on XCD placement: all cross-WG traffic (h values
// and the barrier counter) moves via RELAXED agent-scope atomics, which operate
// at the device coherence point (sc1 path) with NO L2 writeback/invalidate.
// R1 post-mortem: __threadfence + ACQUIRE-polling emitted buffer_wbl2 +
// per-poll buffer_inv -> 55us/step. Never flush caches in a spin loop.
__global__ void __launch_bounds__(256, 1) lstm_layer(
    const unsigned short* __restrict__ xin,   // (B,T,512) bf16 layer input
    unsigned short* __restrict__ seqout,      // (B,T,512) bf16 layer output
    const unsigned short* __restrict__ wih,   // (2048,512) bf16
    const unsigned short* __restrict__ whh,   // (2048,512) bf16
    const float* __restrict__ bih,
    const float* __restrict__ bhh,
    const float* __restrict__ h0,             // (B,512) fp32
    const float* __restrict__ c0,             // (B,512) fp32
    unsigned short* __restrict__ hbuf,        // 2 * B*512 bf16 ping-pong
    unsigned int* __restrict__ bars,          // BGR counters, 128B apart (zeroed)
    float* __restrict__ cout,                 // (B,512) fp32 final c
    int write_seq)
{
  const int tid  = threadIdx.x;
  const int wave = tid >> 6;
  const int lane = tid & 63;
  const int lm   = lane & 15;   // A-frag row (batch) / B-frag row (gate col)
  const int quad = lane >> 4;

  const int bid = blockIdx.x;
  const int grp = bid & 7;      // batch group
  const int kap = bid >> 3;     // hidden slice 0..31
  const int bg0 = grp * BB;

  __shared__ float gates[4][16][68];  // [wave partial][batch][4*16 gate cols + pad]

  // ---- load this WG's weight fragments into registers (held all 1024 steps) ----
  // wave w covers k in [256w, 256w+256): waves 0,1 -> w_ih, waves 2,3 -> w_hh
  const unsigned short* wsel = (wave < 2) ? wih : whh;
  const int kbase = (wave & 1) * 256;
  s8v breg[4][8];
#pragma unroll
  for (int g = 0; g < 4; ++g) {
    const size_t row = (size_t)(g * 512 + kap * 16 + lm);  // gate-major weight row
#pragma unroll
    for (int s = 0; s < 8; ++s)
      breg[g][s] = *(const s8v*)(wsel + row * HID + kbase + s * 32 + quad * 8);
  }

  // ---- per-thread (batch, hidden col) ownership for the elementwise part ----
  const int b_i  = tid >> 4;
  const int kk   = tid & 15;
  const int kcol = kap * 16 + kk;
  const int brow = bg0 + b_i;

  float bias[4];
#pragma unroll
  for (int g = 0; g < 4; ++g) bias[g] = bih[g * 512 + kcol] + bhh[g * 512 + kcol];

  float c = c0[(size_t)brow * HID + kcol];

  // publish h0 through the coherence point (packed u32, even lanes store)
  {
    unsigned short hb0 = f2bf(h0[(size_t)brow * HID + kcol]);
    unsigned hw0 = (unsigned)hb0 | (((unsigned)(unsigned short)__shfl_xor((int)hb0, 1, 64)) << 16);
    if ((tid & 1) == 0)
      __hip_atomic_store((unsigned*)hbuf + (size_t)brow * (HID / 2) + (kcol >> 1),
                         hw0, __ATOMIC_RELAXED, __HIP_MEMORY_SCOPE_AGENT);
  }

  unsigned int* bar = bars + grp * 32;
  unsigned bcount = 0;

  const int arow = bg0 + lm;                       // batch row for A fragments
  const size_t xrow = (size_t)arow * TSEQ * HID;
  const int koffA = kbase + quad * 8;

  // Group barrier: monotonic counter, RELAXED agent atomics only (no cache
  // maintenance). __syncthreads() before the add drains each thread's h stores
  // (compiler emits s_waitcnt vmcnt(0) before s_barrier) -> causal visibility
  // for readers that also go through the coherence point. Bounded spin so a
  // sync failure produces a wrong answer instead of a hang.
#define GROUP_BARRIER()                                                          \
  do {                                                                           \
    __syncthreads();                                                             \
    if (tid == 0) {                                                              \
      ++bcount;                                                                  \
      __hip_atomic_fetch_add(bar, 1u, __ATOMIC_RELAXED, __HIP_MEMORY_SCOPE_AGENT); \
      unsigned tgt = bcount * KSL;                                               \
      int guard = 0;                                                             \
      while (__hip_atomic_load(bar, __ATOMIC_RELAXED, __HIP_MEMORY_SCOPE_AGENT) < tgt \
             && ++guard < (1 << 17)) { __builtin_amdgcn_s_sleep(1); }            \
    }                                                                            \
    __syncthreads();                                                             \
  } while (0)

  GROUP_BARRIER();  // h0 visible group-wide

  for (int t = 0; t < TSEQ; ++t) {
    const unsigned short* hprev = hbuf + (size_t)(t & 1) * BATCH * HID;
    unsigned short* hnext = hbuf + (size_t)((t & 1) ^ 1) * BATCH * HID;

    const unsigned short* xbase = xin + xrow + (size_t)t * HID + koffA;
    const unsigned short* hbase = hprev + (size_t)arow * HID + koffA;

    f4v acc[4];
#pragma unroll
    for (int g = 0; g < 4; ++g) { f4v z = {0.f, 0.f, 0.f, 0.f}; acc[g] = z; }

#pragma unroll
    for (int s = 0; s < 8; ++s) {
      s8v a;
      if (wave < 2) {
        a = *(const s8v*)(xbase + s * 32);          // plain load: read-only input, L2-cached
      } else {
        union { unsigned long long q[2]; s8v v; } ua;  // coherence-point loads: fresh h
        const unsigned long long* p = (const unsigned long long*)(hbase + s * 32);
        ua.q[0] = __hip_atomic_load(p,     __ATOMIC_RELAXED, __HIP_MEMORY_SCOPE_AGENT);
        ua.q[1] = __hip_atomic_load(p + 1, __ATOMIC_RELAXED, __HIP_MEMORY_SCOPE_AGENT);
        a = ua.v;
      }
#pragma unroll
      for (int g = 0; g < 4; ++g)
        acc[g] = __builtin_amdgcn_mfma_f32_16x16x32_bf16(a, breg[g][s], acc[g], 0, 0, 0);
    }

    // D layout (m89-verified): col = lane&15, row = quad*4 + reg
#pragma unroll
    for (int g = 0; g < 4; ++g)
#pragma unroll
      for (int r = 0; r < 4; ++r)
        gates[wave][quad * 4 + r][g * 16 + lm] = acc[g][r];

    __syncthreads();

    float gs[4];
#pragma unroll
    for (int g = 0; g < 4; ++g)
      gs[g] = bias[g] + gates[0][b_i][g * 16 + kk] + gates[1][b_i][g * 16 + kk]
                      + gates[2][b_i][g * 16 + kk] + gates[3][b_i][g * 16 + kk];

    float ig = fsig(gs[0]);
    float fg = fsig(gs[1]);
    float gg = ftanh(gs[2]);
    float og = fsig(gs[3]);
    c = fg * c + ig * gg;
    float h = og * ftanh(c);
    unsigned short hb = f2bf(h);

    // publish h: pack (kk, kk+1) into u32, even lanes store via coherence point
    unsigned hw = (unsigned)hb | (((unsigned)(unsigned short)__shfl_xor((int)hb, 1, 64)) << 16);
    if ((tid & 1) == 0)
      __hip_atomic_store((unsigned*)hnext + (size_t)brow * (HID / 2) + (kcol >> 1),
                         hw, __ATOMIC_RELAXED, __HIP_MEMORY_SCOPE_AGENT);

    if (write_seq) seqout[(size_t)brow * TSEQ * HID + (size_t)t * HID + kcol] = hb;

    GROUP_BARRIER();
  }

  cout[(size_t)brow * HID + kcol] = c;
#undef GROUP_BARRIER
}

extern "C" void kernel_launch(void* const* d_in, const int* in_sizes, int n_in,
                              void* d_out, int out_size, void* d_ws, size_t ws_size,
                              hipStream_t stream)
{
  (void)in_sizes; (void)n_in; (void)out_size;
  const float* x   = (const float*)d_in[0];
  const float* h0  = (const float*)d_in[1];
  const float* c0  = (const float*)d_in[2];
  const float* wih = (const float*)d_in[3];
  const float* whh = (const float*)d_in[4];
  const float* bih = (const float*)d_in[5];
  const float* bhh = (const float*)d_in[6];
  float* out = (float*)d_out;

  const size_t seq_elems = (size_t)BATCH * TSEQ * HID;  // 67,108,864
  const size_t w_elems   = (size_t)LL * G4 * HID;       // 4,194,304

  unsigned short* seqA = (unsigned short*)d_ws;          // layer ping buffer (holds bf16 x first)
  unsigned short* seqB = seqA + seq_elems;               // layer pong buffer
  unsigned short* wihb = seqB + seq_elems;
  unsigned short* whhb = wihb + w_elems;
  unsigned short* hbuf = whhb + w_elems;                 // 2 * B*H
  unsigned int*   bars = (unsigned int*)(hbuf + 2 * (size_t)BATCH * HID);

  size_t need = (2 * seq_elems + 2 * w_elems + 2 * (size_t)BATCH * HID) * 2
              + (size_t)BGR * 32 * 4;
  if (ws_size < need) return;  // fail visibly rather than corrupt memory

  cvt_f32_bf16<<<4096, 256, 0, stream>>>(x,   seqA, (int)(seq_elems / 4));
  cvt_f32_bf16<<<2048, 256, 0, stream>>>(wih, wihb, (int)(w_elems / 4));
  cvt_f32_bf16<<<2048, 256, 0, stream>>>(whh, whhb, (int)(w_elems / 4));

  for (int l = 0; l < LL; ++l) {
    hipMemsetAsync(bars, 0, BGR * 32 * sizeof(unsigned), stream);
    const unsigned short* in_p  = (l & 1) ? seqB : seqA;
    unsigned short*       out_p = (l & 1) ? seqA : seqB;
    const unsigned short* wih_p = wihb + (size_t)l * G4 * HID;
    const unsigned short* whh_p = whhb + (size_t)l * G4 * HID;
    const float* bih_p = bih + l * G4;
    const float* bhh_p = bhh + l * G4;
    const float* h0_p  = h0 + (size_t)l * BATCH * HID;
    const float* c0_p  = c0 + (size_t)l * BATCH * HID;
    float* cout_p = out + (size_t)l * BATCH * HID;
    int wsflag = (l < LL - 1) ? 1 : 0;
    unsigned short* hbuf_p = hbuf;
    unsigned int* bars_p = bars;
    void* args[] = { &in_p, &out_p, &wih_p, &whh_p, &bih_p, &bhh_p,
                     &h0_p, &c0_p, &hbuf_p, &bars_p, &cout_p, &wsflag };
    hipLaunchCooperativeKernel(lstm_layer, dim3(256), dim3(256), args, 0, stream);
  }
}

// Round 4
// 13601.051 us; speedup vs baseline: 9.1594x; 1.2202x over previous
//
#include <hip/hip_runtime.h>
#include <stdint.h>

#define LL 4
#define BATCH 128
#define TSEQ 1024
#define HID 512
#define G4 2048
#define BGR 8     // batch groups (16 batches each)
#define BB 16     // batches per group
#define KSL 32    // hidden-slice WGs per group (16 cols each)

typedef __attribute__((ext_vector_type(8))) short s8v;   // 8 x bf16 fragment
typedef __attribute__((ext_vector_type(4))) float f4v;   // MFMA accumulator

__device__ __forceinline__ unsigned short f2bf(float f) {
  union { float f; unsigned u; } v; v.f = f;
  return (unsigned short)((v.u + 0x7fffu + ((v.u >> 16) & 1u)) >> 16);  // RNE
}

__device__ __forceinline__ float fsig(float x) { return 1.f / (1.f + __expf(-x)); }

__device__ __forceinline__ float ftanh(float x) {
  float a = __builtin_fabsf(x);
  float e = __expf(-2.f * a);
  float t = (1.f - e) / (1.f + e);
  return x < 0.f ? -t : t;
}

__global__ void cvt_f32_bf16(const float* __restrict__ in, unsigned short* __restrict__ out, int n4) {
  int stride = gridDim.x * blockDim.x;
  for (int i = blockIdx.x * blockDim.x + threadIdx.x; i < n4; i += stride) {
    f4v v = ((const f4v*)in)[i];
    union { unsigned short u[4]; unsigned long long d; } o;
    o.u[0] = f2bf(v.x); o.u[1] = f2bf(v.y); o.u[2] = f2bf(v.z); o.u[3] = f2bf(v.w);
    ((unsigned long long*)out)[i] = o.d;
  }
}

// Persistent per-layer LSTM kernel, R4 = R3 structure with the h-fragment
// stride bug fixed (R3 read s*32 BYTES instead of s*32 ELEMENTS between
// K-fragments -> deterministic wrong recurrent GEMM, absmax 1.04).
//  waves 0-1 ("x waves"): compute x-partial for step t+1 during step t
//    (double-buffered LDS plane) -- x GEMM is OFF the h critical path.
//  waves 2-3 ("h waves"): poll the group's 32 per-WG epoch flags with one
//    coalesced vector load + __all (no contended RMW counter, no sleep),
//    then load h via relaxed agent-scope atomics (coherence point; NO cache
//    maintenance -- R1 showed acquire/release fences cost 55us/step).
//  Flag protocol: flags[kap] = t+2 stored by tid0 after syncB drained all
//    h stores; a WG enters step t only after all WGs completed step t-1,
//    which also protects the hbuf ping-pong from write-during-read.
//  Bounded spin: sync failure -> wrong answer, never a hang.
__global__ void __launch_bounds__(256, 1) lstm_layer(
    const unsigned short* __restrict__ xin,   // (B,T,512) bf16 layer input
    unsigned short* __restrict__ seqout,      // (B,T,512) bf16 layer output
    const unsigned short* __restrict__ wih,   // (2048,512) bf16
    const unsigned short* __restrict__ whh,   // (2048,512) bf16
    const float* __restrict__ bih,
    const float* __restrict__ bhh,
    const float* __restrict__ h0,             // (B,512) fp32
    const float* __restrict__ c0,             // (B,512) fp32
    unsigned short* __restrict__ hbuf,        // 2 * B*512 bf16 ping-pong
    unsigned int* __restrict__ bars,          // BGR*32 epoch flags (zeroed)
    float* __restrict__ cout,                 // (B,512) fp32 final c
    int write_seq)
{
  const int tid  = threadIdx.x;
  const int wave = tid >> 6;
  const int lane = tid & 63;
  const int lm   = lane & 15;   // A-frag row (batch) / B-frag row (gate col)
  const int quad = lane >> 4;

  const int bid = blockIdx.x;
  const int grp = bid & 7;      // batch group
  const int kap = bid >> 3;     // hidden slice 0..31
  const int bg0 = grp * BB;

  // xpart: double-buffered x-wave partials (by step parity); hpart: h-wave
  // partials (single-buffered; next write is after syncB of previous step).
  __shared__ float xpart[2][2][16][68];
  __shared__ float hpart[2][16][68];

  const int isH = (wave >= 2);
  const unsigned short* wsel = isH ? whh : wih;
  const int kbase = (wave & 1) * 256;

  // ---- weight fragments resident for all 1024 steps (AGPR/VGPR unified file) ----
  s8v breg[4][8];
#pragma unroll
  for (int g = 0; g < 4; ++g) {
    const size_t row = (size_t)(g * 512 + kap * 16 + lm);
#pragma unroll
    for (int s = 0; s < 8; ++s)
      breg[g][s] = *(const s8v*)(wsel + row * HID + kbase + s * 32 + quad * 8);
  }

  // ---- per-thread (batch, hidden col) cell ownership ----
  const int b_i  = tid >> 4;
  const int kk   = tid & 15;
  const int kcol = kap * 16 + kk;
  const int brow = bg0 + b_i;

  float bias[4];
#pragma unroll
  for (int g = 0; g < 4; ++g) bias[g] = bih[g * 512 + kcol] + bhh[g * 512 + kcol];

  float c = c0[(size_t)brow * HID + kcol];

  // publish h0 through the coherence point (packed u32, even lanes store)
  {
    unsigned short hb0 = f2bf(h0[(size_t)brow * HID + kcol]);
    unsigned hw0 = (unsigned)hb0 | (((unsigned)(unsigned short)__shfl_xor((int)hb0, 1, 64)) << 16);
    if ((tid & 1) == 0)
      __hip_atomic_store((unsigned*)hbuf + (size_t)brow * (HID / 2) + (kcol >> 1),
                         hw0, __ATOMIC_RELAXED, __HIP_MEMORY_SCOPE_AGENT);
  }

  unsigned int* flags = bars + grp * 32;

  const int arow = bg0 + lm;                       // batch row for A fragments
  const size_t xrowbase = (size_t)arow * TSEQ * HID;
  const int koffA = kbase + quad * 8;

  // ---- x prologue: partial for step 0 into xpart[0] ----
  if (!isH) {
    const unsigned short* xb = xin + xrowbase + koffA;  // t = 0
    s8v af[8];
#pragma unroll
    for (int s = 0; s < 8; ++s) af[s] = *(const s8v*)(xb + s * 32);
    f4v acc[4];
#pragma unroll
    for (int g = 0; g < 4; ++g) { f4v z = {0.f, 0.f, 0.f, 0.f}; acc[g] = z; }
#pragma unroll
    for (int s = 0; s < 8; ++s)
#pragma unroll
      for (int g = 0; g < 4; ++g)
        acc[g] = __builtin_amdgcn_mfma_f32_16x16x32_bf16(af[s], breg[g][s], acc[g], 0, 0, 0);
#pragma unroll
    for (int g = 0; g < 4; ++g)
#pragma unroll
      for (int r = 0; r < 4; ++r)
        xpart[0][wave][quad * 4 + r][g * 16 + lm] = acc[g][r];
  }

  __syncthreads();                   // drains h0 stores of every wave
  if (tid == 0)
    __hip_atomic_store(&flags[kap], 1u, __ATOMIC_RELAXED, __HIP_MEMORY_SCOPE_AGENT);

  for (int t = 0; t < TSEQ; ++t) {
    if (!isH) {
      // ---- x waves: partial for step t+1 (off critical path) ----
      if (t + 1 < TSEQ) {
        const unsigned short* xb = xin + xrowbase + (size_t)(t + 1) * HID + koffA;
        s8v af[8];
#pragma unroll
        for (int s = 0; s < 8; ++s) af[s] = *(const s8v*)(xb + s * 32);
        f4v acc[4];
#pragma unroll
        for (int g = 0; g < 4; ++g) { f4v z = {0.f, 0.f, 0.f, 0.f}; acc[g] = z; }
#pragma unroll
        for (int s = 0; s < 8; ++s)
#pragma unroll
          for (int g = 0; g < 4; ++g)
            acc[g] = __builtin_amdgcn_mfma_f32_16x16x32_bf16(af[s], breg[g][s], acc[g], 0, 0, 0);
#pragma unroll
        for (int g = 0; g < 4; ++g)
#pragma unroll
          for (int r = 0; r < 4; ++r)
            xpart[(t + 1) & 1][wave][quad * 4 + r][g * 16 + lm] = acc[g][r];
      }
    } else {
      // ---- h waves: poll flags (coalesced 32-lane load, no RMW, no sleep) ----
      const unsigned tgt = (unsigned)(t + 1);
      for (int guard = 0; guard < (1 << 15); ++guard) {
        unsigned f = __hip_atomic_load(&flags[lane & 31], __ATOMIC_RELAXED,
                                       __HIP_MEMORY_SCOPE_AGENT);
        if (__all((int)(f >= tgt))) break;
      }
      asm volatile("" ::: "memory");  // no compiler motion of h loads above the poll
      // ---- load h(t-1) fragments via coherence point, then MFMA ----
      // fragment s covers k = kbase + s*32 + quad*8 .. +7  ->  byte offset
      // s*64 from (arow*HID + koffA); as ull (8B) units that is s*8. (R3 bug:
      // used s*4 = half stride.)
      const unsigned short* hprev = hbuf + (size_t)(t & 1) * BATCH * HID;
      const unsigned long long* hb64 =
          (const unsigned long long*)(hprev + (size_t)arow * HID + koffA);
      union { unsigned long long q[16]; s8v v[8]; } ua;
#pragma unroll
      for (int s = 0; s < 8; ++s) {
        ua.q[2 * s]     = __hip_atomic_load(hb64 + s * 8,     __ATOMIC_RELAXED, __HIP_MEMORY_SCOPE_AGENT);
        ua.q[2 * s + 1] = __hip_atomic_load(hb64 + s * 8 + 1, __ATOMIC_RELAXED, __HIP_MEMORY_SCOPE_AGENT);
      }
      f4v acc[4];
#pragma unroll
      for (int g = 0; g < 4; ++g) { f4v z = {0.f, 0.f, 0.f, 0.f}; acc[g] = z; }
#pragma unroll
      for (int s = 0; s < 8; ++s)
#pragma unroll
        for (int g = 0; g < 4; ++g)
          acc[g] = __builtin_amdgcn_mfma_f32_16x16x32_bf16(ua.v[s], breg[g][s], acc[g], 0, 0, 0);
      // D layout (m89-verified): col = lane&15, row = quad*4 + reg
#pragma unroll
      for (int g = 0; g < 4; ++g)
#pragma unroll
        for (int r = 0; r < 4; ++r)
          hpart[wave - 2][quad * 4 + r][g * 16 + lm] = acc[g][r];
    }

    __syncthreads();   // sync A: partials visible

    float gs[4];
#pragma unroll
    for (int g = 0; g < 4; ++g)
      gs[g] = bias[g]
            + xpart[t & 1][0][b_i][g * 16 + kk] + xpart[t & 1][1][b_i][g * 16 + kk]
            + hpart[0][b_i][g * 16 + kk]        + hpart[1][b_i][g * 16 + kk];

    float ig = fsig(gs[0]);
    float fg = fsig(gs[1]);
    float gg = ftanh(gs[2]);
    float og = fsig(gs[3]);
    c = fg * c + ig * gg;
    float h = og * ftanh(c);
    unsigned short hb = f2bf(h);

    // publish h(t): pack (kk, kk^1) into u32, even lanes store via coherence point
    unsigned hw = (unsigned)hb | (((unsigned)(unsigned short)__shfl_xor((int)hb, 1, 64)) << 16);
    unsigned short* hnext = hbuf + (size_t)((t & 1) ^ 1) * BATCH * HID;
    if ((tid & 1) == 0) {
      __hip_atomic_store((unsigned*)hnext + (size_t)brow * (HID / 2) + (kcol >> 1),
                         hw, __ATOMIC_RELAXED, __HIP_MEMORY_SCOPE_AGENT);
      if (write_seq)
        ((unsigned*)seqout)[((size_t)brow * TSEQ + t) * (HID / 2) + (kcol >> 1)] = hw;
    }

    __syncthreads();   // sync B: every wave's h stores drained (vmcnt(0) + s_barrier)
    if (tid == 0)
      __hip_atomic_store(&flags[kap], (unsigned)(t + 2), __ATOMIC_RELAXED,
                         __HIP_MEMORY_SCOPE_AGENT);
  }

  cout[(size_t)brow * HID + kcol] = c;
}

extern "C" void kernel_launch(void* const* d_in, const int* in_sizes, int n_in,
                              void* d_out, int out_size, void* d_ws, size_t ws_size,
                              hipStream_t stream)
{
  (void)in_sizes; (void)n_in; (void)out_size;
  const float* x   = (const float*)d_in[0];
  const float* h0  = (const float*)d_in[1];
  const float* c0  = (const float*)d_in[2];
  const float* wih = (const float*)d_in[3];
  const float* whh = (const float*)d_in[4];
  const float* bih = (const float*)d_in[5];
  const float* bhh = (const float*)d_in[6];
  float* out = (float*)d_out;

  const size_t seq_elems = (size_t)BATCH * TSEQ * HID;  // 67,108,864
  const size_t w_elems   = (size_t)LL * G4 * HID;       // 4,194,304

  unsigned short* seqA = (unsigned short*)d_ws;          // layer ping buffer (holds bf16 x first)
  unsigned short* seqB = seqA + seq_elems;               // layer pong buffer
  unsigned short* wihb = seqB + seq_elems;
  unsigned short* whhb = wihb + w_elems;
  unsigned short* hbuf = whhb + w_elems;                 // 2 * B*H
  unsigned int*   bars = (unsigned int*)(hbuf + 2 * (size_t)BATCH * HID);

  size_t need = (2 * seq_elems + 2 * w_elems + 2 * (size_t)BATCH * HID) * 2
              + (size_t)BGR * 32 * 4;
  if (ws_size < need) return;  // fail visibly rather than corrupt memory

  cvt_f32_bf16<<<4096, 256, 0, stream>>>(x,   seqA, (int)(seq_elems / 4));
  cvt_f32_bf16<<<2048, 256, 0, stream>>>(wih, wihb, (int)(w_elems / 4));
  cvt_f32_bf16<<<2048, 256, 0, stream>>>(whh, whhb, (int)(w_elems / 4));

  for (int l = 0; l < LL; ++l) {
    hipMemsetAsync(bars, 0, BGR * 32 * sizeof(unsigned), stream);
    const unsigned short* in_p  = (l & 1) ? seqB : seqA;
    unsigned short*       out_p = (l & 1) ? seqA : seqB;
    const unsigned short* wih_p = wihb + (size_t)l * G4 * HID;
    const unsigned short* whh_p = whhb + (size_t)l * G4 * HID;
    const float* bih_p = bih + l * G4;
    const float* bhh_p = bhh + l * G4;
    const float* h0_p  = h0 + (size_t)l * BATCH * HID;
    const float* c0_p  = c0 + (size_t)l * BATCH * HID;
    float* cout_p = out + (size_t)l * BATCH * HID;
    int wsflag = (l < LL - 1) ? 1 : 0;
    unsigned short* hbuf_p = hbuf;
    unsigned int* bars_p = bars;
    void* args[] = { &in_p, &out_p, &wih_p, &whh_p, &bih_p, &bhh_p,
                     &h0_p, &c0_p, &hbuf_p, &bars_p, &cout_p, &wsflag };
    hipLaunchCooperativeKernel(lstm_layer, dim3(256), dim3(256), args, 0, stream);
  }
}